// Round 6
// baseline (118.378 us; speedup 1.0000x reference)
//
#include <hip/hip_runtime.h>
#include <hip/hip_bf16.h>

// Problem constants: B=16, N=64, T=128, D=8, N_EMB=64, N_H=128, BN=1024,
// F_in=128, gates=512.

typedef _Float16 half8 __attribute__((ext_vector_type(8)));
typedef float f32x4 __attribute__((ext_vector_type(4)));

__device__ __forceinline__ float rcp_(float x){ return __builtin_amdgcn_rcpf(x); }
__device__ __forceinline__ float sigmoidf_(float x){ return rcp_(1.0f + __expf(-x)); }
__device__ __forceinline__ float tanhf_(float x){ return fmaf(-2.0f, rcp_(1.0f + __expf(2.0f*x)), 1.0f); }

// ---------------------------------------------------------------------------
// Kernel 1: repack W_ih (512x128) and W_hh (512x128) into f16 MFMA B-fragment
// order. wfrag[w][i][lane][e], i = src*16 + kk*4 + cti;
//   j = 16*w + 128*cti + (lane&15); k = 32*kk + 8*(lane>>4) + e
// ---------------------------------------------------------------------------
__global__ __launch_bounds__(256) void prep_kernel(const float* __restrict__ W_ih,
                                                   const float* __restrict__ W_hh,
                                                   _Float16* __restrict__ wfrag){
  int gid = blockIdx.x*256 + threadIdx.x;   // [0, 16384)
  int w    = gid >> 11;
  int i    = (gid >> 6) & 31;
  int lane = gid & 63;
  int src = i >> 4, kk = (i >> 2) & 3, cti = i & 3;
  int j = 16*w + 128*cti + (lane & 15);
  int kbase = 32*kk + 8*(lane >> 4);
  const float* W = src ? W_hh : W_ih;
  _Float16* dst = wfrag + (size_t)(((w*32 + i)*64 + lane) * 8);
  #pragma unroll
  for (int e = 0; e < 8; e++) dst[e] = (_Float16)W[j*128 + kbase + e];
}

// ---------------------------------------------------------------------------
// Kernel 2: GCN v2 — one WAVE per (b,t) slice; 512 blocks x 256 thr.
// dist via readlane broadcast; rowsum via ones-column; A@x (K=64) and
// concat-proj+bias (K=32, block-diagonal W2 with bias row k=16).
// Epilogue stages each 16x128 tile in LDS then does coalesced half8 stores.
// feat[t][b*64+n][f] f16.
// ---------------------------------------------------------------------------
__global__ __launch_bounds__(256) void gcn2_kernel(const float* __restrict__ x,
    const float* __restrict__ Wc, const float* __restrict__ bc,
    const float* __restrict__ Ws, const float* __restrict__ bs,
    _Float16* __restrict__ feat){
  __shared__ _Float16 W2[32*136];       // [k][f] block-diag: Ws | Wc | bias row
  __shared__ _Float16 As16[4][64*72];   // per-wave unnormalized w, padded
  __shared__ _Float16 zs16[4][64*40];   // per-wave z = [x | y | 1 | 0], padded

  int tid = threadIdx.x;
  int wav = tid >> 6, lane = tid & 63;
  int slice = blockIdx.x*4 + wav;       // 0..2047
  int b = slice >> 7, t = slice & 127;
  int c = lane & 15, kq = lane >> 4;

  // build W2 (all 256 threads)
  for (int idx = tid; idx < 32*136; idx += 256){
    int k = idx / 136, f = idx - k*136;
    float v = 0.f;
    if (f < 64){
      if (k < 8) v = Ws[f*8 + k];
      else if (k == 16) v = bs[f];
    } else if (f < 128){
      if (k >= 8 && k < 16) v = Wc[(f-64)*8 + (k-8)];
      else if (k == 16) v = bc[f-64];
    }
    W2[idx] = (_Float16)v;
  }

  _Float16* As_w = &As16[wav][0];
  _Float16* zs_w = &zs16[wav][0];

  // per-lane x row (f32 in regs), write z row: [x(0-7) | 1@8 | 1@16 | zeros]
  const float* xrow = x + ((size_t)(b*64 + lane)*128 + t)*8;
  float4 xlo = *(const float4*)xrow;
  float4 xhi = *(const float4*)(xrow + 4);
  float xr[8] = {xlo.x, xlo.y, xlo.z, xlo.w, xhi.x, xhi.y, xhi.z, xhi.w};
  {
    half8 hx;
    #pragma unroll
    for (int d = 0; d < 8; d++) hx[d] = (_Float16)xr[d];
    half8 h1 = (half8){(_Float16)1.f,0,0,0,0,0,0,0};
    half8 h0 = (half8){0,0,0,0,0,0,0,0};
    *(half8*)(zs_w + lane*40)      = hx;
    *(half8*)(zs_w + lane*40 + 8)  = h1;  // col8 = 1 (rowsum col), 9-15 = 0
    *(half8*)(zs_w + lane*40 + 16) = h1;  // col16 = 1 (bias row), 17-23 = 0
    *(half8*)(zs_w + lane*40 + 24) = h0;  // 24-31 = 0
  }

  // pairwise 1/dist: lane = col n; x-rows broadcast from regs via readlane
  #pragma unroll 4
  for (int m = 0; m < 64; m++){
    float d2 = 0.f;
    #pragma unroll
    for (int d = 0; d < 8; d++){
      float xm = __int_as_float(__builtin_amdgcn_readlane(__float_as_int(xr[d]), m));
      float df = xm - xr[d];
      d2 = fmaf(df, df, d2);
    }
    float wv = (m == lane) ? 0.f : __frsqrt_rn(d2);
    As_w[m*72 + lane] = (_Float16)wv;
  }

  __syncthreads();   // W2 visible

  // projection B-fragments (loop-invariant): wfr[nt][e] = W2[8kq+e][16nt+c]
  half8 wfr[8];
  #pragma unroll
  for (int nt = 0; nt < 8; nt++){
    half8 tmp;
    #pragma unroll
    for (int e = 0; e < 8; e++) tmp[e] = W2[(8*kq + e)*136 + 16*nt + c];
    wfr[nt] = tmp;
  }

  // A@x B-fragments: x_aug[k][n] (cols 0-7 = x, col8 = ones)
  half8 bx0, bx1;
  {
    half8 t0, t1;
    #pragma unroll
    for (int e = 0; e < 8; e++){
      t0[e] = zs_w[(8*kq + e)*40 + c];
      t1[e] = zs_w[(32 + 8*kq + e)*40 + c];
    }
    bx0 = t0; bx1 = t1;
  }

  const f32x4 zero4 = (f32x4){0.f,0.f,0.f,0.f};

  // A@x + row-normalize -> y into zs cols 8-15
  #pragma unroll
  for (int mt = 0; mt < 4; mt++){
    half8 aa0 = *(const half8*)(As_w + (16*mt + c)*72 + 8*kq);
    half8 aa1 = *(const half8*)(As_w + (16*mt + c)*72 + 32 + 8*kq);
    f32x4 cax = __builtin_amdgcn_mfma_f32_16x16x32_f16(aa0, bx0, zero4, 0,0,0);
    cax = __builtin_amdgcn_mfma_f32_16x16x32_f16(aa1, bx1, cax, 0,0,0);
    int bidx = ((lane & 48) | 8) << 2;   // pull rowsum from lane (kq*16+8)
    #pragma unroll
    for (int e = 0; e < 4; e++){
      float rs = __int_as_float(__builtin_amdgcn_ds_bpermute(bidx, __float_as_int(cax[e])));
      float yv = cax[e] * rcp_(fmaxf(rs, 1e-12f));
      if (c < 8) zs_w[(16*mt + 4*kq + e)*40 + 8 + c] = (_Float16)yv;
    }
  }

  // concat-projection (K=32: x|y|bias-ones) + SELU; stage tile in LDS (reuse
  // the now-dead As region, stride 132 -> <=2-way banks), then coalesced
  // half8 global stores.
  _Float16* st = As_w;    // 16*132 = 2112 f16 <= 4608 available
  int rr = lane >> 2, qq = lane & 3;
  #pragma unroll
  for (int mt = 0; mt < 4; mt++){
    half8 az = *(const half8*)(zs_w + (16*mt + c)*40 + 8*kq);
    #pragma unroll
    for (int nt = 0; nt < 8; nt++){
      f32x4 pc = __builtin_amdgcn_mfma_f32_16x16x32_f16(az, wfr[nt], zero4, 0,0,0);
      #pragma unroll
      for (int e = 0; e < 4; e++){
        float v = pc[e];
        v = (v > 0.f) ? 1.0507009873554805f*v
                      : 1.7580993408473766f*(__expf(v) - 1.0f);
        st[(4*kq + e)*132 + 16*nt + c] = (_Float16)v;
      }
    }
    asm volatile("s_waitcnt lgkmcnt(0)" ::: "memory");  // wave-local stage done
    size_t obase = ((size_t)t*1024 + (size_t)b*64 + 16*mt + rr)*128 + qq*32;
    #pragma unroll
    for (int j = 0; j < 4; j++){
      half8 pk = *(const half8*)(st + rr*132 + qq*32 + 8*j);
      *(half8*)(feat + obase + 8*j) = pk;
    }
    asm volatile("s_waitcnt lgkmcnt(0)" ::: "memory");  // reads done before next mt overwrites
  }
}

// ---------------------------------------------------------------------------
// Kernel 3: persistent fused LSTM. 256 blocks x 512 thr, 4 samples/block.
// Per 4-step group, ONE M=16 tile (4 samples x 4 t-locals) computes the
// x-gates (16 MFMA/wave, bias folded via C-operand); double-buffered so
// gates(g+1) are built during group g. Step order: issue h ds_reads ->
// x-slab MFMAs (cover LDS latency) -> h-MFMAs -> cell. 1 raw s_barrier/step.
// ---------------------------------------------------------------------------
__global__ __launch_bounds__(512, 2) void lstm3_kernel(
    const _Float16* __restrict__ wfrag, const _Float16* __restrict__ feat,
    const float* __restrict__ b_ih, const float* __restrict__ b_hh,
    float* __restrict__ out){
  int tid = threadIdx.x;
  int w = tid >> 6, l = tid & 63;
  int blk = blockIdx.x;            // 0..255
  int r = l & 15, kq = l >> 4;
  __shared__ _Float16 h_lds[2][544];   // [parity][sample*134 + hidden]

  half8 bf[32];
  const _Float16* wb = wfrag + (size_t)w*(32*64*8);
  #pragma unroll
  for (int i = 0; i < 32; i++)
    bf[i] = *(const half8*)(wb + (size_t)(i*64 + l)*8);

  f32x4 biasx4[4];
  #pragma unroll
  for (int cti = 0; cti < 4; cti++){
    int j = 16*w + 128*cti + r;
    float bv = b_ih[j] + b_hh[j];
    biasx4[cti] = (f32x4){bv, bv, bv, bv};
  }

  for (int idx = tid; idx < 544; idx += 512) h_lds[0][idx] = (_Float16)0.f;

  float cc = 0.f;
  const f32x4 zero4 = (f32x4){0.f,0.f,0.f,0.f};

  // x-slab A rows: row = sample*4 + tl; lane (r,kq) covers row r, k=32kk+8kq+e
  const size_t arow_s = (size_t)(blk*4 + (r >> 2));
  const int atl = r & 3;
  const int habase = (r & 3)*134 + 8*kq;
  const int hwoff = kq*134 + 16*w + r;

  half8 afA[4], afB[4];
  f32x4 accxA[4], accxB[4];

#define LOADAF(AF, G) {                                                       \
    int gg = (G) > 31 ? 31 : (G);                                             \
    const _Float16* fb = feat + ((size_t)(4*gg + atl)*1024 + arow_s)*128 + 8*kq; \
    AF[0] = *(const half8*)(fb);                                              \
    AF[1] = *(const half8*)(fb + 32);                                         \
    AF[2] = *(const half8*)(fb + 64);                                         \
    AF[3] = *(const half8*)(fb + 96);                                         \
  }

  // prologue: gates(0) built directly; afB <- feat(1); afA <- feat(2)
  LOADAF(afA, 0)
  #pragma unroll
  for (int cti = 0; cti < 4; cti++)
    accxA[cti] = __builtin_amdgcn_mfma_f32_16x16x32_f16(afA[0], bf[cti], biasx4[cti], 0,0,0);
  #pragma unroll
  for (int kk = 1; kk < 4; kk++)
    #pragma unroll
    for (int cti = 0; cti < 4; cti++)
      accxA[cti] = __builtin_amdgcn_mfma_f32_16x16x32_f16(afA[kk], bf[kk*4+cti], accxA[cti], 0,0,0);
  LOADAF(afB, 1)
  LOADAF(afA, 2)
  __syncthreads();

#define SEL(A) ((kq & 2) ? ((kq & 1) ? A[3] : A[2]) : ((kq & 1) ? A[1] : A[0]))

#define STEP3(TL, ACCU, ACCB, AFB_, GN)                                       \
  {                                                                           \
    half8 ha[4];                                                              \
    _Pragma("unroll")                                                         \
    for (int kk = 0; kk < 4; kk++)                                            \
      ha[kk] = *(const half8*)(&h_lds[(TL)&1][habase + 32*kk]);               \
    _Pragma("unroll")                                                         \
    for (int cti = 0; cti < 4; cti++){                                        \
      if ((TL) == 0)                                                          \
        ACCB[cti] = __builtin_amdgcn_mfma_f32_16x16x32_f16(AFB_[0], bf[cti], biasx4[cti], 0,0,0); \
      else                                                                    \
        ACCB[cti] = __builtin_amdgcn_mfma_f32_16x16x32_f16(AFB_[(TL)], bf[(TL)*4+cti], ACCB[cti], 0,0,0); \
    }                                                                         \
    if ((TL) == 3) LOADAF(AFB_, GN)                                           \
    f32x4 acc0, acc1, acc2, acc3;                                             \
    acc0 = __builtin_amdgcn_mfma_f32_16x16x32_f16(ha[0], bf[16], zero4, 0,0,0); \
    acc1 = __builtin_amdgcn_mfma_f32_16x16x32_f16(ha[0], bf[17], zero4, 0,0,0); \
    acc2 = __builtin_amdgcn_mfma_f32_16x16x32_f16(ha[0], bf[18], zero4, 0,0,0); \
    acc3 = __builtin_amdgcn_mfma_f32_16x16x32_f16(ha[0], bf[19], zero4, 0,0,0); \
    _Pragma("unroll")                                                         \
    for (int kk = 1; kk < 4; kk++){                                           \
      acc0 = __builtin_amdgcn_mfma_f32_16x16x32_f16(ha[kk], bf[16+kk*4+0], acc0, 0,0,0); \
      acc1 = __builtin_amdgcn_mfma_f32_16x16x32_f16(ha[kk], bf[16+kk*4+1], acc1, 0,0,0); \
      acc2 = __builtin_amdgcn_mfma_f32_16x16x32_f16(ha[kk], bf[16+kk*4+2], acc2, 0,0,0); \
      acc3 = __builtin_amdgcn_mfma_f32_16x16x32_f16(ha[kk], bf[16+kk*4+3], acc3, 0,0,0); \
    }                                                                         \
    float g0_ = SEL(acc0) + ACCU[0][(TL)];                                    \
    float g1_ = SEL(acc1) + ACCU[1][(TL)];                                    \
    float g2_ = SEL(acc2) + ACCU[2][(TL)];                                    \
    float g3_ = SEL(acc3) + ACCU[3][(TL)];                                    \
    float c_ = fmaf(sigmoidf_(g1_), cc, sigmoidf_(g0_)*tanhf_(g2_));          \
    cc = c_;                                                                  \
    float h_ = sigmoidf_(g3_)*tanhf_(c_);                                     \
    h_lds[1-((TL)&1)][hwoff] = (_Float16)h_;                                  \
    asm volatile("s_waitcnt lgkmcnt(0)" ::: "memory");                        \
    __builtin_amdgcn_s_barrier();                                             \
  }

  for (int i = 0; i < 16; ++i){
    STEP3(0, accxA, accxB, afB, 0)
    STEP3(1, accxA, accxB, afB, 0)
    STEP3(2, accxA, accxB, afB, 0)
    STEP3(3, accxA, accxB, afB, 2*i+3)
    STEP3(0, accxB, accxA, afA, 0)
    STEP3(1, accxB, accxA, afA, 0)
    STEP3(2, accxB, accxA, afA, 0)
    STEP3(3, accxB, accxA, afA, 2*i+4)
  }
#undef STEP3
#undef SEL
#undef LOADAF

  // t=127 (TL=3) wrote h_lds[0]; last barrier already executed. The lane's
  // own slot holds exactly its (sample kq, hidden 16w+r) output.
  out[((size_t)blk*4 + kq)*128 + 16*w + r] = (float)h_lds[0][hwoff];
}

// ---------------------------------------------------------------------------
extern "C" void kernel_launch(void* const* d_in, const int* in_sizes, int n_in,
                              void* d_out, int out_size, void* d_ws, size_t ws_size,
                              hipStream_t stream) {
  const float* x    = (const float*)d_in[0];
  const float* Wc   = (const float*)d_in[3];
  const float* bc   = (const float*)d_in[4];
  const float* Ws   = (const float*)d_in[5];
  const float* bs   = (const float*)d_in[6];
  const float* W_ih = (const float*)d_in[7];
  const float* W_hh = (const float*)d_in[8];
  const float* b_ih = (const float*)d_in[9];
  const float* b_hh = (const float*)d_in[10];
  float* out = (float*)d_out;

  // ws: [0,256KB) wfrag f16 | [256KB, +33.5MB) feat f16
  _Float16* wfrag = (_Float16*)d_ws;
  _Float16* feat  = (_Float16*)((char*)d_ws + 262144);

  prep_kernel<<<64, 256, 0, stream>>>(W_ih, W_hh, wfrag);
  gcn2_kernel<<<512, 256, 0, stream>>>(x, Wc, bc, Ws, bs, feat);
  lstm3_kernel<<<256, 512, 0, stream>>>(wfrag, feat, b_ih, b_hh, out);
}